// Round 4
// baseline (260.386 us; speedup 1.0000x reference)
//
#include <hip/hip_runtime.h>

typedef __attribute__((ext_vector_type(8))) _Float16 half8;
typedef __attribute__((ext_vector_type(4))) float f32x4;

#define GAS(p) ((const __attribute__((address_space(1))) void*)(p))
#define LAS(p) ((__attribute__((address_space(3))) void*)(p))

// ---------------------------------------------------------------------------
// Merged prepass. Blocks [0,4096): feat (B,F) fp32 -> fp16 A-fragments.
// Blocks [4096,4576): W1 (E,F,H) fp32 -> fp16 B-fragments.
// Fragment = contiguous 1 KB [16 rows][32 k]; 8-elem group (row,k8) at slot
// k8*16+row so consuming lane l reads bytes [16l,16l+16) = A[m=l&15][k=(l>>4)*8+j].
// ---------------------------------------------------------------------------
__global__ __launch_bounds__(256) void cvt_pre(const float* __restrict__ feat,
                                               const float* __restrict__ W1,
                                               _Float16* __restrict__ A16,
                                               _Float16* __restrict__ W1T) {
    if (blockIdx.x < 4096) {
        int gid = blockIdx.x * 256 + threadIdx.x;      // 1,048,576 groups of 8
        int k8   = gid & 3;
        int m    = (gid >> 2) & 15;
        int frag = gid >> 6;                           // [bt(64)][kc(32)][mf(8)]
        int mf = frag & 7;
        int kc = (frag >> 3) & 31;
        int bt = frag >> 8;
        int b  = bt * 128 + mf * 16 + m;
        int f0 = kc * 32 + k8 * 8;
        const float4* src = (const float4*)(feat + (size_t)b * 1024 + f0);
        float4 v0 = src[0], v1 = src[1];
        half8 o;
        o[0] = (_Float16)v0.x; o[1] = (_Float16)v0.y;
        o[2] = (_Float16)v0.z; o[3] = (_Float16)v0.w;
        o[4] = (_Float16)v1.x; o[5] = (_Float16)v1.y;
        o[6] = (_Float16)v1.z; o[7] = (_Float16)v1.w;
        *(half8*)(A16 + ((size_t)frag * 64 + k8 * 16 + m) * 8) = o;
    } else {
        int gid = (blockIdx.x - 4096) * 256 + threadIdx.x;  // 122,880 groups
        int k8   = gid & 3;
        int n    = (gid >> 2) & 15;
        int frag = gid >> 6;                           // [e(30)][kc(32)][nf(2)]
        int nf = frag & 1;
        int kc = (frag >> 1) & 31;
        int e  = frag >> 6;
        int h  = nf * 16 + n;
        int f0 = kc * 32 + k8 * 8;
        const float* src = W1 + ((size_t)e * 1024 + f0) * 32 + h;
        half8 o;
#pragma unroll
        for (int j = 0; j < 8; ++j) o[j] = (_Float16)src[j * 32];
        *(half8*)(W1T + ((size_t)frag * 64 + k8 * 16 + n) * 8) = o;
    }
}

// ---------------------------------------------------------------------------
// Kernel 1: block = (128 b-rows, 4 emotions) = 128x128 tile; wave tile 64x64
// (4x4 f32x4 accs). Per kc2: 8 ds_read_b128 : 16 MFMA. E padded to 32;
// e>=30: clamped param loads, stores skipped (W1T pad region = finite 0xAA
// garbage, MFMA harmless). wbuf layout (E,B,NB).
// ---------------------------------------------------------------------------
__global__ __launch_bounds__(256) void gemm_mlp(
    const _Float16* __restrict__ A16, const _Float16* __restrict__ W1T,
    const float* __restrict__ b1, const float* __restrict__ W2,
    const float* __restrict__ b2, const float* __restrict__ wts,
    float* __restrict__ wbuf) {
    __shared__ __align__(16) unsigned char smem[39296];
    unsigned char* Ash = smem;                        // 16 KB stage (K-loop)
    unsigned char* Bsh = smem + 16384;                // 16 KB stage (K-loop)
    float* h_sh = (float*)smem;                       // 128*33*4 B (post-loop)
    float* w2s = (float*)(smem + 32768);              // 4*384 floats
    float* cb2 = (float*)(smem + 32768 + 6144);       // 48 floats
    float* ews = cb2 + 48;                            // 48 floats

    const int tid = threadIdx.x;
    const int e0 = blockIdx.x * 4;   // emotion group 0..7 (E padded to 32)
    const int bt = blockIdx.y;       // 0..63
    const int w  = tid >> 6, l = tid & 63;
    const int q  = l >> 4, lc = l & 15;
    const int wm = w & 1, wn = w >> 1;   // wave tile: rows wm*64, cols wn*64

    for (int i = tid; i < 1536; i += 256) {
        int ee = e0 + i / 384; if (ee >= 30) ee = 0;
        w2s[i] = W2[ee * 384 + (i % 384)];
    }
    if (tid < 48) {
        int ee = e0 + tid / 12; if (ee >= 30) ee = 0;
        cb2[tid] = b2[ee * 12 + (tid % 12)];
        ews[tid] = __expf(wts[ee * 12 + (tid % 12)]);
    }

    const _Float16* Abase = A16 + (size_t)bt * 131072;

    f32x4 zero = {0.f, 0.f, 0.f, 0.f};
    f32x4 acc[4][4];
#pragma unroll
    for (int i = 0; i < 4; ++i)
#pragma unroll
        for (int j = 0; j < 4; ++j) acc[i][j] = zero;

    for (int it = 0; it < 16; ++it) {
        const _Float16* Ait = Abase + it * 8192;   // 16 KB (kc = 2it, 2it+1)
#pragma unroll
        for (int i = 0; i < 4; ++i) {
            int f = w * 4 + i;                     // A frags [kc2(2)][mf(8)]
            __builtin_amdgcn_global_load_lds(GAS(Ait + f * 512 + l * 8),
                                             LAS(Ash + f * 1024), 16, 0, 0);
        }
#pragma unroll
        for (int i = 0; i < 4; ++i) {
            int f = w * 4 + i;                     // B frags [kc2(2)][eo(4)][nf(2)]
            int kc2 = f >> 3, sub = f & 7, eo = sub >> 1, nf = sub & 1;
            __builtin_amdgcn_global_load_lds(
                GAS(W1T + ((size_t)(e0 + eo) * 64 + (2 * it + kc2) * 2 + nf) * 512 + l * 8),
                LAS(Bsh + f * 1024), 16, 0, 0);
        }
        __syncthreads();
#pragma unroll
        for (int kc2 = 0; kc2 < 2; ++kc2) {
            half8 a[4], bv[4];
#pragma unroll
            for (int mf = 0; mf < 4; ++mf)
                a[mf] = *(half8*)(Ash + (kc2 * 8 + wm * 4 + mf) * 1024 + l * 16);
#pragma unroll
            for (int nf = 0; nf < 4; ++nf)
                bv[nf] = *(half8*)(Bsh + (kc2 * 8 + wn * 4 + nf) * 1024 + l * 16);
#pragma unroll
            for (int mf = 0; mf < 4; ++mf)
#pragma unroll
                for (int nf = 0; nf < 4; ++nf)
                    acc[mf][nf] = __builtin_amdgcn_mfma_f32_16x16x32_f16(
                        a[mf], bv[nf], acc[mf][nf], 0, 0, 0);
        }
        __syncthreads();
    }

    const float SC = 1.0507009873554805f, AL = 1.6732632423543772f;
    const int m2 = tid >> 1, sub = tid & 1;

#pragma unroll
    for (int eo = 0; eo < 4; ++eo) {
        int ec = (e0 + eo < 30) ? e0 + eo : 0;   // clamped for param loads
        // owning waves (wn == eo>>1) write h -> h_sh[128][33]
        if (wn == (eo >> 1)) {
            int nf0 = (eo & 1) * 2;
#pragma unroll
            for (int j = 0; j < 2; ++j) {
                float b1v = b1[ec * 32 + j * 16 + lc];
#pragma unroll
                for (int mf = 0; mf < 4; ++mf)
#pragma unroll
                    for (int r = 0; r < 4; ++r) {
                        int m   = wm * 64 + mf * 16 + q * 4 + r;  // row=(l>>4)*4+r
                        int col = j * 16 + lc;                    // col=l&15
                        float x = acc[mf][nf0 + j][r] + b1v;
                        float hv = x > 0.f ? SC * x : SC * AL * (__expf(x) - 1.f);
                        h_sh[m * 33 + col] = hv;
                    }
            }
        }
        __syncthreads();

        // GEMM2 + normalize: 2 threads per row, 6 outputs each
        float u[6] = {0.f, 0.f, 0.f, 0.f, 0.f, 0.f};
        const float* hrow = h_sh + m2 * 33;
        const float* wbase = w2s + eo * 384 + sub * 6;
#pragma unroll 8
        for (int h = 0; h < 32; ++h) {
            float hv = hrow[h];
            const float* wr = wbase + h * 12;
#pragma unroll
            for (int j = 0; j < 6; ++j) u[j] += hv * wr[j];
        }
        float sew = 0.f;
#pragma unroll
        for (int i = 0; i < 12; ++i) sew += ews[eo * 12 + i];
        sew = fmaxf(sew, 1e-12f);
        float sabs = 0.f;
#pragma unroll
        for (int j = 0; j < 6; ++j) {
            u[j] += cb2[eo * 12 + sub * 6 + j] + ews[eo * 12 + sub * 6 + j] / sew;
            sabs += fabsf(u[j]);
        }
        sabs += __shfl_xor(sabs, 1);
        float inv = 1.f / fmaxf(sabs, 1e-12f);
        if (e0 + eo < 30) {
            int b = bt * 128 + m2;
            float* dst = wbuf + (size_t)(e0 + eo) * 98304 + b * 12 + sub * 6;
#pragma unroll
            for (int j = 0; j < 6; ++j) dst[j] = u[j] * inv;
        }
        __syncthreads();   // protect h_sh before next eo overwrites
    }
}

// ---------------------------------------------------------------------------
// Kernel 2: mixed = w . dist, softmax over L. 8 rows/block; dist register-
// cached. No max pass: sum|w|=1 and dist in [0,1) => |mixed| < 1, exp safe.
// ---------------------------------------------------------------------------
__global__ __launch_bounds__(256) void mix_softmax(
    const float* __restrict__ dist, const float* __restrict__ wbuf,
    float* __restrict__ out) {
    __shared__ float wsm[8 * 360];                    // [m][e][n]
    const int tid = threadIdx.x;
    const int b0 = blockIdx.x * 8;
    for (int i = tid; i < 2880; i += 256) {
        int e = i / 96, r = i - e * 96;               // r = m*12+n
        wsm[(r / 12) * 360 + e * 12 + (r % 12)] = wbuf[(size_t)e * 98304 + b0 * 12 + r];
    }
    __syncthreads();
    const int m = tid >> 5, l4 = tid & 31;
    const int b = b0 + m;
    const float* dbase = dist + (size_t)b * 1536 + l4 * 4;
    f32x4 d[12];
#pragma unroll
    for (int n = 0; n < 12; ++n) d[n] = *(const f32x4*)(dbase + n * 128);
    const float* wrow = wsm + m * 360;
    for (int e = 0; e < 30; ++e) {
        const float* wr = wrow + e * 12;
        f32x4 a = {0.f, 0.f, 0.f, 0.f};
#pragma unroll
        for (int n = 0; n < 12; ++n) a += wr[n] * d[n];
        f32x4 ex;
        ex[0] = __expf(a[0]); ex[1] = __expf(a[1]);
        ex[2] = __expf(a[2]); ex[3] = __expf(a[3]);
        float sm = ex[0] + ex[1] + ex[2] + ex[3];
#pragma unroll
        for (int s = 16; s >= 1; s >>= 1) sm += __shfl_xor(sm, s);
        f32x4 o = ex * (1.f / sm);
        *(f32x4*)(out + ((size_t)e * 8192 + b) * 128 + l4 * 4) = o;
    }
}

// ---------------------------------------------------------------------------
extern "C" void kernel_launch(void* const* d_in, const int* in_sizes, int n_in,
                              void* d_out, int out_size, void* d_ws, size_t ws_size,
                              hipStream_t stream) {
    const float* dist = (const float*)d_in[0];   // (B, NB, L)
    const float* feat = (const float*)d_in[1];   // (B, F)
    const float* wts  = (const float*)d_in[2];   // (E,1,NB,1)
    const float* W1   = (const float*)d_in[3];   // (E, F, H)
    const float* b1   = (const float*)d_in[4];   // (E, H)
    const float* W2   = (const float*)d_in[5];   // (E, H, NB)
    const float* b2   = (const float*)d_in[6];   // (E, NB)
    float* out = (float*)d_out;                  // (E, B, L)

    _Float16* A16 = (_Float16*)d_ws;                            // 16,777,216 B
    _Float16* W1T = (_Float16*)((char*)d_ws + 16777216);        //  4,194,304 B (32 e, pad)
    float*   wbuf = (float*)((char*)d_ws + 16777216 + 4194304); // 11,796,480 B (E,B,NB)

    cvt_pre<<<4576, 256, 0, stream>>>(feat, W1, A16, W1T);
    dim3 g1(8, 64);
    gemm_mlp<<<g1, 256, 0, stream>>>(A16, W1T, b1, W2, b2, wts, wbuf);
    mix_softmax<<<1024, 256, 0, stream>>>(dist, wbuf, out);
}